// Round 2
// baseline (319.345 us; speedup 1.0000x reference)
//
#include <hip/hip_runtime.h>

// arHOCA: L=200 positions, Q=21 alphabet, H=128 hidden, B=256 batch.
// x is one-hot => all "x @ W" contractions are gather-sums over idx[b,l].
//
// DCA mask subtlety (faithful to reference): mask loop is `for i in range(Q)`,
// so only row-blocks 1..20 / col-blocks 0..19 are active, and mask[d,c]=1 iff
// block(c) < block(d). => out_dca[b,j] = sum_{l=j/Q+1}^{20} DW[l*Q+idx[b,l], j].
//
// ws layout: idx (B*L int, 204800B) | h1T [199][128][256] f32 (26083328B)
//            | h2T [199][128][256] f32 (26083328B)  => needs ~52.4 MB of d_ws.

#define Lc   200
#define Qc   21
#define Hc   128
#define Bc   256
#define LQc  4200
#define LM1c 199

// ---------------- K0: idx[b,l] = argmax_c x[b,l,c] ----------------
__global__ __launch_bounds__(256) void k_idx(const float* __restrict__ x,
                                             int* __restrict__ idxp) {
    int t = blockIdx.x * 256 + threadIdx.x;
    if (t >= Bc * Lc) return;
    const float* p = x + (size_t)t * Qc;
    int id = 0;
#pragma unroll
    for (int c = 0; c < Qc; ++c) id = (p[c] > 0.5f) ? c : id;
    idxp[t] = id;
}

// ---------------- K1: DCA gather + bias + out0 (w0+b0) ----------------
// out[b, j] = bias[j] + sum_{l = j/Q+1 .. 20} DW[l*Q+idx[b,l], j]  (+ w0+b0 for j<Q)
__global__ __launch_bounds__(256) void k_dca(const float* __restrict__ DW,
                                             const float* __restrict__ bias,
                                             const float* __restrict__ w0,
                                             const float* __restrict__ b0,
                                             const int* __restrict__ idxp,
                                             float* __restrict__ out) {
    const int b = blockIdx.x / 5, chunk = blockIdx.x % 5;
    const int j0 = chunk * 1024 + threadIdx.x * 4;
    if (j0 >= LQc) return;
    float a[4];
    const float4 bv = *(const float4*)(bias + j0);
    a[0] = bv.x; a[1] = bv.y; a[2] = bv.z; a[3] = bv.w;
    if (j0 < Qc) {
#pragma unroll
        for (int e = 0; e < 4; ++e) {
            int j = j0 + e;
            if (j < Qc) a[e] += w0[j] + b0[j];
        }
    }
    // DCA contributions: col j gets row-block l iff j < l*Q, l in [1, Q-1].
    if (j0 < (Qc - 1) * Qc) {
        const int* idxb = idxp + b * Lc;
        const int lmin = j0 / Qc + 1;
        for (int l = lmin; l < Qc; ++l) {
            const int iv = idxb[l];
            const float4 v = *(const float4*)(DW + (size_t)(l * Qc + iv) * LQc + j0);
            const int thr = l * Qc;  // contribute iff j < l*Q
            a[0] += (j0     < thr) ? v.x : 0.f;
            a[1] += (j0 + 1 < thr) ? v.y : 0.f;
            a[2] += (j0 + 2 < thr) ? v.z : 0.f;
            a[3] += (j0 + 3 < thr) ? v.w : 0.f;
        }
    }
    float4 o = {a[0], a[1], a[2], a[3]};
    *(float4*)(out + (size_t)b * LQc + j0) = o;
}

// ---------------- K2: h1T[l][k][b] = lrelu(sum_{l'<=l} W1[l, l'Q+idx[b,l'], k] + b1[l,k]) ----------------
// wg = (l, batch-group of 16). Lane <-> 4 h-values so each gather is a coalesced
// 64-lane float4 read of a W1 row (512B). Two batches per wave-instruction.
__global__ __launch_bounds__(256) void k_h1(const float* __restrict__ W1,
                                            const float* __restrict__ b1,
                                            const int* __restrict__ idxp,
                                            float* __restrict__ h1T) {
    const int l  = blockIdx.x >> 4;
    const int bg = blockIdx.x & 15;
    const int t = threadIdx.x;
    const int w = t >> 6, lane = t & 63;
    const int jb = lane >> 5;        // which batch within the half-wave pair
    const int hq = lane & 31;        // h-quad index: h = hq*4 .. hq*4+3
    const int ba = bg * 16 + w * 4 + jb;  // batch for pass A
    const int bb = ba + 2;                // batch for pass B
    const float* Wl = W1 + (size_t)l * LQc * Hc + hq * 4;
    float aA[4] = {0, 0, 0, 0}, aB[4] = {0, 0, 0, 0};
    for (int lp = 0; lp <= l; ++lp) {
        const int ia = idxp[ba * Lc + lp];
        const int ib = idxp[bb * Lc + lp];
        const float4 va = *(const float4*)(Wl + (size_t)(lp * Qc + ia) * Hc);
        const float4 vb = *(const float4*)(Wl + (size_t)(lp * Qc + ib) * Hc);
        aA[0] += va.x; aA[1] += va.y; aA[2] += va.z; aA[3] += va.w;
        aB[0] += vb.x; aB[1] += vb.y; aB[2] += vb.z; aB[3] += vb.w;
    }
    const float4 bbv = *(const float4*)(b1 + l * Hc + hq * 4);
    const float bz[4] = {bbv.x, bbv.y, bbv.z, bbv.w};
    __shared__ float tile[16][Hc];
#pragma unroll
    for (int e = 0; e < 4; ++e) {
        float ra = aA[e] + bz[e];
        float rb = aB[e] + bz[e];
        ra = (ra >= 0.f) ? ra : 0.1f * ra;
        rb = (rb >= 0.f) ? rb : 0.1f * rb;
        tile[w * 4 + jb][hq * 4 + e]     = ra;
        tile[w * 4 + jb + 2][hq * 4 + e] = rb;
    }
    __syncthreads();
    // cooperative transposed store: h1T[l][k][bg*16 + bi]
    const int k = t >> 1, bo = (t & 1) * 8;
    float4 o0, o1;
    o0.x = tile[bo + 0][k]; o0.y = tile[bo + 1][k]; o0.z = tile[bo + 2][k]; o0.w = tile[bo + 3][k];
    o1.x = tile[bo + 4][k]; o1.y = tile[bo + 5][k]; o1.z = tile[bo + 6][k]; o1.w = tile[bo + 7][k];
    float* dst = h1T + ((size_t)l * Hc + k) * Bc + bg * 16 + bo;
    *(float4*)dst = o0;
    *(float4*)(dst + 4) = o1;
}

// ---------------- K3: h2T[l][n][b] = lrelu(sum_k h1T[l][k][b] * W2[l][k][n] + b2[l][n]) ----------------
// fp32 tiled GEMM: M=128 (batch half), N=128, K=128 in 8 steps of 16. 8x8 reg tile/thread.
__global__ __launch_bounds__(256) void k_h2(const float* __restrict__ h1T,
                                            const float* __restrict__ W2,
                                            const float* __restrict__ b2,
                                            float* __restrict__ h2T) {
    const int l = blockIdx.x >> 1;
    const int bbase = (blockIdx.x & 1) * 128;
    const int t = threadIdx.x;
    const int tx = t & 15, ty = t >> 4;
    __shared__ float As[16][Hc];
    __shared__ float Bs[16][Hc];
    __shared__ float Ts[32][Hc];
    float acc[8][8];
#pragma unroll
    for (int i = 0; i < 8; ++i)
#pragma unroll
        for (int j = 0; j < 8; ++j) acc[i][j] = 0.f;
    const int skk = t >> 4, sms = (t & 15) * 8;
    const float* h1l = h1T + (size_t)l * Hc * Bc;
    const float* W2l = W2 + (size_t)l * Hc * Hc;
    for (int ks = 0; ks < 8; ++ks) {
        const int kb = ks * 16 + skk;
        *(float4*)&As[skk][sms]     = *(const float4*)(h1l + (size_t)kb * Bc + bbase + sms);
        *(float4*)&As[skk][sms + 4] = *(const float4*)(h1l + (size_t)kb * Bc + bbase + sms + 4);
        *(float4*)&Bs[skk][sms]     = *(const float4*)(W2l + (size_t)kb * Hc + sms);
        *(float4*)&Bs[skk][sms + 4] = *(const float4*)(W2l + (size_t)kb * Hc + sms + 4);
        __syncthreads();
#pragma unroll
        for (int k = 0; k < 16; ++k) {
            float av[8], bv[8];
            *(float4*)&av[0] = *(const float4*)&As[k][ty * 8];
            *(float4*)&av[4] = *(const float4*)&As[k][ty * 8 + 4];
            *(float4*)&bv[0] = *(const float4*)&Bs[k][tx * 8];
            *(float4*)&bv[4] = *(const float4*)&Bs[k][tx * 8 + 4];
#pragma unroll
            for (int i = 0; i < 8; ++i)
#pragma unroll
                for (int j = 0; j < 8; ++j) acc[i][j] += av[i] * bv[j];
        }
        __syncthreads();
    }
    float bz[8];
    *(float4*)&bz[0] = *(const float4*)(b2 + l * Hc + tx * 8);
    *(float4*)&bz[4] = *(const float4*)(b2 + l * Hc + tx * 8 + 4);
    float res[8][8];
#pragma unroll
    for (int i = 0; i < 8; ++i)
#pragma unroll
        for (int j = 0; j < 8; ++j) {
            float v = acc[i][j] + bz[j];
            res[i][j] = (v >= 0.f) ? v : 0.1f * v;
        }
    // transpose-store via LDS in 4 chunks of 32 n-rows: h2T[l][n][bbase+m]
    for (int c = 0; c < 4; ++c) {
        if ((tx >> 2) == c) {
#pragma unroll
            for (int i = 0; i < 8; ++i)
#pragma unroll
                for (int j = 0; j < 8; ++j) Ts[(tx & 3) * 8 + j][ty * 8 + i] = res[i][j];
        }
        __syncthreads();
        const int r = t >> 3, m2 = (t & 7) * 16;
        float* dst = h2T + ((size_t)l * Hc + c * 32 + r) * Bc + bbase + m2;
#pragma unroll
        for (int u = 0; u < 4; ++u) *(float4*)(dst + u * 4) = *(const float4*)&Ts[r][m2 + u * 4];
        __syncthreads();
    }
}

// ---------------- K4: out[b, l+1, q] += sum_k h2T[l][k][b] * Wout[l][k][q] + bout[l][q] ----------------
__global__ __launch_bounds__(128) void k_out(const float* __restrict__ h2T,
                                             const float* __restrict__ Wout,
                                             const float* __restrict__ bout,
                                             float* __restrict__ out) {
    const int l = blockIdx.x >> 1;
    const int bh = blockIdx.x & 1;
    const int t = threadIdx.x;  // 0..127
    __shared__ float wl[Hc * Qc];
    __shared__ float bl[Qc];
    const float* wsrc = Wout + (size_t)l * Hc * Qc;
    for (int i = t; i < Hc * Qc; i += 128) wl[i] = wsrc[i];
    if (t < Qc) bl[t] = bout[l * Qc + t];
    __syncthreads();
    const int b = bh * 128 + t;
    float acc[Qc];
#pragma unroll
    for (int q = 0; q < Qc; ++q) acc[q] = bl[q];
    const float* h2l = h2T + (size_t)l * Hc * Bc + b;
    for (int k = 0; k < Hc; ++k) {
        const float av = h2l[(size_t)k * Bc];
        const float* wr = &wl[k * Qc];
#pragma unroll
        for (int q = 0; q < Qc; ++q) acc[q] += av * wr[q];
    }
    float* op = out + ((size_t)b * Lc + (l + 1)) * Qc;
#pragma unroll
    for (int q = 0; q < Qc; ++q) op[q] += acc[q];
}

extern "C" void kernel_launch(void* const* d_in, const int* in_sizes, int n_in,
                              void* d_out, int out_size, void* d_ws, size_t ws_size,
                              hipStream_t stream) {
    const float* x    = (const float*)d_in[0];
    const float* bias = (const float*)d_in[1];
    const float* DW   = (const float*)d_in[2];
    const float* w0   = (const float*)d_in[3];
    const float* b0   = (const float*)d_in[4];
    const float* W1   = (const float*)d_in[5];
    const float* b1   = (const float*)d_in[6];
    const float* W2   = (const float*)d_in[7];
    const float* b2   = (const float*)d_in[8];
    const float* Wout = (const float*)d_in[9];
    const float* bout = (const float*)d_in[10];
    float* out = (float*)d_out;

    int*   idxp = (int*)d_ws;
    float* h1T  = (float*)((char*)d_ws + 204800);
    float* h2T  = (float*)((char*)d_ws + 204800 + 26083328);

    k_idx<<<(Bc * Lc + 255) / 256, 256, 0, stream>>>(x, idxp);
    k_dca<<<Bc * 5, 256, 0, stream>>>(DW, bias, w0, b0, idxp, out);
    k_h1<<<LM1c * 16, 256, 0, stream>>>(W1, b1, idxp, h1T);
    k_h2<<<LM1c * 2, 256, 0, stream>>>(h1T, W2, b2, h2T);
    k_out<<<LM1c * 2, 128, 0, stream>>>(h2T, Wout, bout, out);
}

// Round 3
// 297.787 us; speedup vs baseline: 1.0724x; 1.0724x over previous
//
#include <hip/hip_runtime.h>

// arHOCA: L=200 positions, Q=21 alphabet, H=128 hidden, B=256 batch.
// x is one-hot => all "x @ W" contractions are gather-sums over idx[b,l].
//
// DCA mask subtlety (faithful to reference): mask loop is `for i in range(Q)`,
// so only row-blocks 1..20 / col-blocks 0..19 are active, and mask[d,c]=1 iff
// block(c) < block(d). => out_dca[b,j] = sum_{l=j/Q+1}^{20} DW[l*Q+idx[b,l], j].
//
// ws layout: idx (B*L int, 204800B) | h1T [199][128][256] f32 (26083328B)
//            | h2T [199][128][256] f32 (26083328B)  => needs ~52.4 MB of d_ws.

#define Lc   200
#define Qc   21
#define Hc   128
#define Bc   256
#define LQc  4200
#define LM1c 199
#define TPAD 132  // LDS row stride (floats): 128 + 4 keeps float4 align, spreads banks

// ---------------- K0: idx[b,l] = argmax_c x[b,l,c] ----------------
__global__ __launch_bounds__(256) void k_idx(const float* __restrict__ x,
                                             int* __restrict__ idxp) {
    int t = blockIdx.x * 256 + threadIdx.x;
    if (t >= Bc * Lc) return;
    const float* p = x + (size_t)t * Qc;
    int id = 0;
#pragma unroll
    for (int c = 0; c < Qc; ++c) id = (p[c] > 0.5f) ? c : id;
    idxp[t] = id;
}

// ---------------- K1: DCA gather + bias + out0 (w0+b0) ----------------
// out[b, j] = bias[j] + sum_{l = j/Q+1 .. 20} DW[l*Q+idx[b,l], j]  (+ w0+b0 for j<Q)
__global__ __launch_bounds__(256) void k_dca(const float* __restrict__ DW,
                                             const float* __restrict__ bias,
                                             const float* __restrict__ w0,
                                             const float* __restrict__ b0,
                                             const int* __restrict__ idxp,
                                             float* __restrict__ out) {
    const int b = blockIdx.x / 5, chunk = blockIdx.x % 5;
    const int j0 = chunk * 1024 + threadIdx.x * 4;
    if (j0 >= LQc) return;
    float a[4];
    const float4 bv = *(const float4*)(bias + j0);
    a[0] = bv.x; a[1] = bv.y; a[2] = bv.z; a[3] = bv.w;
    if (j0 < Qc) {
#pragma unroll
        for (int e = 0; e < 4; ++e) {
            int j = j0 + e;
            if (j < Qc) a[e] += w0[j] + b0[j];
        }
    }
    // DCA contributions: col j gets row-block l iff j < l*Q, l in [1, Q-1].
    if (j0 < (Qc - 1) * Qc) {
        const int* idxb = idxp + b * Lc;
        const int lmin = j0 / Qc + 1;
        for (int l = lmin; l < Qc; ++l) {
            const int iv = idxb[l];
            const float4 v = *(const float4*)(DW + (size_t)(l * Qc + iv) * LQc + j0);
            const int thr = l * Qc;  // contribute iff j < l*Q
            a[0] += (j0     < thr) ? v.x : 0.f;
            a[1] += (j0 + 1 < thr) ? v.y : 0.f;
            a[2] += (j0 + 2 < thr) ? v.z : 0.f;
            a[3] += (j0 + 3 < thr) ? v.w : 0.f;
        }
    }
    float4 o = {a[0], a[1], a[2], a[3]};
    *(float4*)(out + (size_t)b * LQc + j0) = o;
}

// ---------------- K2 (rewritten): LDS-broadcast accumulate ----------------
// h1T[l][h][b] = lrelu(sum_{lp<=l} W1[l, lp*Q+idx[b,lp], h] + b1[l,h])
// Block = (l, batch-half). Per step lp: stage the 21 candidate rows (10.5 KB)
// in LDS once; each thread broadcast-reads its batch's row. Each W1 element is
// fetched from HBM once per batch-half (2x total; dup absorbed by L2/L3).
// Thread t: hh=t>>7 (h-half), bl=t&127 (batch). acc[64] in VGPRs.
__global__ __launch_bounds__(256) void k_h1(const float* __restrict__ W1,
                                            const float* __restrict__ b1,
                                            const int* __restrict__ idxp,
                                            float* __restrict__ h1T) {
    const int l  = 198 - (int)(blockIdx.x >> 1);  // longest blocks first
    const int bh = blockIdx.x & 1;
    const int t  = threadIdx.x;
    const int hh = t >> 7;
    const int bl = t & 127;
    const int b  = bh * 128 + bl;
    const int rowoff = hh * 64;

    __shared__ float tile[2][Qc * TPAD];
    __shared__ float bsh[Hc];

    const float* Wl = W1 + (size_t)l * (LQc * Hc);
    const int* idxb = idxp + (size_t)b * Lc;

    if (t < Hc) bsh[t] = b1[l * Hc + t];

    // stage tile 0 (2688 floats = 672 float4)
    for (int i = t; i < 672; i += 256) {
        const float4 v = *(const float4*)(Wl + 4 * i);
        *(float4*)&tile[0][(i >> 5) * TPAD + (i & 31) * 4] = v;
    }
    __syncthreads();

    float acc[64];
#pragma unroll
    for (int j = 0; j < 64; ++j) acc[j] = 0.f;

    int cur = 0;
    for (int lp = 0; lp <= l; ++lp) {
        // prefetch tile lp+1 into regs (issue before the LDS-bound accumulate)
        float4 p0, p1, p2;
        const bool has = (lp < l);
        if (has) {
            const float* src = Wl + (size_t)(lp + 1) * (Qc * Hc);
            p0 = *(const float4*)(src + 4 * t);
            p1 = *(const float4*)(src + 4 * (t + 256));
            if (t < 160) p2 = *(const float4*)(src + 4 * (t + 512));
        }
        const int row = idxb[lp];
        const float* tp = &tile[cur][row * TPAD + rowoff];
#pragma unroll
        for (int j = 0; j < 16; ++j) {
            const float4 v = *(const float4*)(tp + 4 * j);
            acc[4 * j + 0] += v.x;
            acc[4 * j + 1] += v.y;
            acc[4 * j + 2] += v.z;
            acc[4 * j + 3] += v.w;
        }
        __syncthreads();  // all reads of tile[cur] done (it is overwritten next iter)
        if (has) {
            float* dst = tile[cur ^ 1];
            *(float4*)&dst[((t)       >> 5) * TPAD + (t & 31) * 4]         = p0;
            *(float4*)&dst[((t + 256) >> 5) * TPAD + ((t + 256) & 31) * 4] = p1;
            if (t < 160)
                *(float4*)&dst[((t + 512) >> 5) * TPAD + ((t + 512) & 31) * 4] = p2;
        }
        __syncthreads();  // tile[cur^1] ready for next iter
        cur ^= 1;
    }

    // bias + lrelu + transposed store h1T[l][h][b]; lanes (bl) are consecutive => coalesced
    float* outp = h1T + ((size_t)l * Hc + rowoff) * Bc + b;
#pragma unroll
    for (int k = 0; k < 64; ++k) {
        float v = acc[k] + bsh[rowoff + k];
        v = (v >= 0.f) ? v : 0.1f * v;
        outp[(size_t)k * Bc] = v;
    }
}

// ---------------- K3: h2T[l][n][b] = lrelu(sum_k h1T[l][k][b] * W2[l][k][n] + b2[l][n]) ----------------
// fp32 tiled GEMM: M=128 (batch half), N=128, K=128 in 8 steps of 16. 8x8 reg tile/thread.
__global__ __launch_bounds__(256) void k_h2(const float* __restrict__ h1T,
                                            const float* __restrict__ W2,
                                            const float* __restrict__ b2,
                                            float* __restrict__ h2T) {
    const int l = blockIdx.x >> 1;
    const int bbase = (blockIdx.x & 1) * 128;
    const int t = threadIdx.x;
    const int tx = t & 15, ty = t >> 4;
    __shared__ float As[16][Hc];
    __shared__ float Bs[16][Hc];
    __shared__ float Ts[32][Hc];
    float acc[8][8];
#pragma unroll
    for (int i = 0; i < 8; ++i)
#pragma unroll
        for (int j = 0; j < 8; ++j) acc[i][j] = 0.f;
    const int skk = t >> 4, sms = (t & 15) * 8;
    const float* h1l = h1T + (size_t)l * Hc * Bc;
    const float* W2l = W2 + (size_t)l * Hc * Hc;
    for (int ks = 0; ks < 8; ++ks) {
        const int kb = ks * 16 + skk;
        *(float4*)&As[skk][sms]     = *(const float4*)(h1l + (size_t)kb * Bc + bbase + sms);
        *(float4*)&As[skk][sms + 4] = *(const float4*)(h1l + (size_t)kb * Bc + bbase + sms + 4);
        *(float4*)&Bs[skk][sms]     = *(const float4*)(W2l + (size_t)kb * Hc + sms);
        *(float4*)&Bs[skk][sms + 4] = *(const float4*)(W2l + (size_t)kb * Hc + sms + 4);
        __syncthreads();
#pragma unroll
        for (int k = 0; k < 16; ++k) {
            float av[8], bv[8];
            *(float4*)&av[0] = *(const float4*)&As[k][ty * 8];
            *(float4*)&av[4] = *(const float4*)&As[k][ty * 8 + 4];
            *(float4*)&bv[0] = *(const float4*)&Bs[k][tx * 8];
            *(float4*)&bv[4] = *(const float4*)&Bs[k][tx * 8 + 4];
#pragma unroll
            for (int i = 0; i < 8; ++i)
#pragma unroll
                for (int j = 0; j < 8; ++j) acc[i][j] += av[i] * bv[j];
        }
        __syncthreads();
    }
    float bz[8];
    *(float4*)&bz[0] = *(const float4*)(b2 + l * Hc + tx * 8);
    *(float4*)&bz[4] = *(const float4*)(b2 + l * Hc + tx * 8 + 4);
    float res[8][8];
#pragma unroll
    for (int i = 0; i < 8; ++i)
#pragma unroll
        for (int j = 0; j < 8; ++j) {
            float v = acc[i][j] + bz[j];
            res[i][j] = (v >= 0.f) ? v : 0.1f * v;
        }
    // transpose-store via LDS in 4 chunks of 32 n-rows: h2T[l][n][bbase+m]
    for (int c = 0; c < 4; ++c) {
        if ((tx >> 2) == c) {
#pragma unroll
            for (int i = 0; i < 8; ++i)
#pragma unroll
                for (int j = 0; j < 8; ++j) Ts[(tx & 3) * 8 + j][ty * 8 + i] = res[i][j];
        }
        __syncthreads();
        const int r = t >> 3, m2 = (t & 7) * 16;
        float* dst = h2T + ((size_t)l * Hc + c * 32 + r) * Bc + bbase + m2;
#pragma unroll
        for (int u = 0; u < 4; ++u) *(float4*)(dst + u * 4) = *(const float4*)&Ts[r][m2 + u * 4];
        __syncthreads();
    }
}

// ---------------- K4: out[b, l+1, q] += sum_k h2T[l][k][b] * Wout[l][k][q] + bout[l][q] ----------------
__global__ __launch_bounds__(128) void k_out(const float* __restrict__ h2T,
                                             const float* __restrict__ Wout,
                                             const float* __restrict__ bout,
                                             float* __restrict__ out) {
    const int l = blockIdx.x >> 1;
    const int bh = blockIdx.x & 1;
    const int t = threadIdx.x;  // 0..127
    __shared__ float wl[Hc * Qc];
    __shared__ float bl[Qc];
    const float* wsrc = Wout + (size_t)l * Hc * Qc;
    for (int i = t; i < Hc * Qc; i += 128) wl[i] = wsrc[i];
    if (t < Qc) bl[t] = bout[l * Qc + t];
    __syncthreads();
    const int b = bh * 128 + t;
    float acc[Qc];
#pragma unroll
    for (int q = 0; q < Qc; ++q) acc[q] = bl[q];
    const float* h2l = h2T + (size_t)l * Hc * Bc + b;
    for (int k = 0; k < Hc; ++k) {
        const float av = h2l[(size_t)k * Bc];
        const float* wr = &wl[k * Qc];
#pragma unroll
        for (int q = 0; q < Qc; ++q) acc[q] += av * wr[q];
    }
    float* op = out + ((size_t)b * Lc + (l + 1)) * Qc;
#pragma unroll
    for (int q = 0; q < Qc; ++q) op[q] += acc[q];
}

extern "C" void kernel_launch(void* const* d_in, const int* in_sizes, int n_in,
                              void* d_out, int out_size, void* d_ws, size_t ws_size,
                              hipStream_t stream) {
    const float* x    = (const float*)d_in[0];
    const float* bias = (const float*)d_in[1];
    const float* DW   = (const float*)d_in[2];
    const float* w0   = (const float*)d_in[3];
    const float* b0   = (const float*)d_in[4];
    const float* W1   = (const float*)d_in[5];
    const float* b1   = (const float*)d_in[6];
    const float* W2   = (const float*)d_in[7];
    const float* b2   = (const float*)d_in[8];
    const float* Wout = (const float*)d_in[9];
    const float* bout = (const float*)d_in[10];
    float* out = (float*)d_out;

    int*   idxp = (int*)d_ws;
    float* h1T  = (float*)((char*)d_ws + 204800);
    float* h2T  = (float*)((char*)d_ws + 204800 + 26083328);

    k_idx<<<(Bc * Lc + 255) / 256, 256, 0, stream>>>(x, idxp);
    k_dca<<<Bc * 5, 256, 0, stream>>>(DW, bias, w0, b0, idxp, out);
    k_h1<<<LM1c * 2, 256, 0, stream>>>(W1, b1, idxp, h1T);
    k_h2<<<LM1c * 2, 256, 0, stream>>>(h1T, W2, b2, h2T);
    k_out<<<LM1c * 2, 128, 0, stream>>>(h2T, Wout, bout, out);
}